// Round 15
// baseline (102.228 us; speedup 1.0000x reference)
//
#include <hip/hip_runtime.h>
#include <hip/hip_bf16.h>

// LoRALinear: y = x @ W^T + b + 1.0 * ((x @ A^T) @ B^T)
// W_eff = W + B@A (bf16, ws[0..2MB)).
// Fused GEMM 256x256x64, R14 = R13 pipeline with 32x32x16 MFMA:
//   ~17% fewer MFMA-pipe cycles (2495 vs 2075 TF ceiling), half the MFMA
//   instruction count. Staging/swizzle/sync structure IDENTICAL to R13
//   (1 barrier/tile, B triple-buffered, A reg-staged fused cvt).
// Fragment layout (m74/m101): A/B lane holds row|col l&31, k=(l>>5)*8+j;
// C/D col=lane&31, row=(reg&3)+8*(reg>>2)+4*(lane>>5).

typedef __bf16 bf16;
typedef bf16 bf16x8 __attribute__((ext_vector_type(8)));
typedef float f32x4 __attribute__((ext_vector_type(4)));
typedef float f32x16 __attribute__((ext_vector_type(16)));

constexpr int K_DIM = 1024;
constexpr int N_DIM = 1024;
constexpr int M_DIM = 8 * 4096;
constexpr int NT = K_DIM / 64;  // 16 K-tiles
constexpr float SCALING = 16.0f / 16.0f;

// ---------------- W_eff = W + B@A, cast to bf16 ----------------
__global__ __launch_bounds__(256) void weff_kernel(
    const float* __restrict__ W, const float* __restrict__ A,
    const float* __restrict__ B, bf16* __restrict__ weff) {
  const int o = blockIdx.x;
  const int tid = threadIdx.x;
  float br[16];
#pragma unroll
  for (int r = 0; r < 16; ++r) br[r] = B[o * 16 + r];
#pragma unroll
  for (int j = 0; j < 4; ++j) {
    const int k = tid + j * 256;
    float s = W[o * K_DIM + k];
#pragma unroll
    for (int r = 0; r < 16; ++r) s += SCALING * br[r] * A[r * K_DIM + k];
    weff[o * K_DIM + k] = (bf16)s;
  }
}

// ---------------- fused 1-barrier 256x256 GEMM (32x32x16) ----------------
__device__ __forceinline__ void async16(const void* g, void* l) {
  __builtin_amdgcn_global_load_lds(
      (const __attribute__((address_space(1))) void*)g,
      (__attribute__((address_space(3))) void*)l, 16, 0, 0);
}
#define BAR() __builtin_amdgcn_s_barrier()
#define LGKM(n) asm volatile("s_waitcnt lgkmcnt(" #n ")" ::: "memory")
#define VMW(n) asm volatile("s_waitcnt vmcnt(" #n ")" ::: "memory")
#define MFMA32(d, a, b) \
  d = __builtin_amdgcn_mfma_f32_32x32x16_bf16(a, b, d, 0, 0, 0)

// LDS (bf16 elems, 81920 = 160 KB):
//   A bufs: (t&1)*16384 ; B bufs: 32768 + (t%3)*16384
// Row = 64 bf16 = 8 chunks of 16 B; stored chunk s holds global chunk s^(row&7).

__global__ __launch_bounds__(512, 2) void gemm32m(
    const float* __restrict__ Xf, const bf16* __restrict__ Wf,
    const float* __restrict__ bias, float* __restrict__ Y) {
  __shared__ __align__(16) bf16 smem[81920];  // 160 KiB

  const int tid = threadIdx.x;
  const int lane = tid & 63;
  const int wid = tid >> 6;
  const int wm = wid >> 2;  // 0..1
  const int wn = wid & 3;   // 0..3
  const int l31 = lane & 31;
  const int lh = lane >> 5;  // 0..1

  // XCD-aware bijective swizzle (512 % 8 == 0)
  const int bid = blockIdx.x;
  const int wgid = (bid & 7) * 64 + (bid >> 3);
  const int bm = wgid >> 2;  // 0..127
  const int bn = wgid & 3;   // 0..3
  const long m0 = (long)bm * 256;
  const int n0 = bn * 256;

  // ---- B staging (global_load_lds, pre-swizzled source) ----
  const int srow = tid >> 3;               // 0..63
  const int gch = (tid & 7) ^ (srow & 7);  // inverse of read swizzle
  const bf16* wsrc = Wf + (long)(n0 + srow) * K_DIM + gch * 8;
  auto stageB = [&](int tt, int h, int buf) {
    bf16* dst = smem + 32768 + buf * 16384 + h * 8192 + tid * 8;
    const bf16* s = wsrc + (long)h * 128 * K_DIM + tt * 64;
    async16(s, dst);
    async16(s + 64 * K_DIM, dst + 4096);
  };

  // ---- A staging (reg-staged fp32 -> bf16, swizzled ds_write) ----
  const int arow = tid >> 2;  // 0..127
  const int acp = tid & 3;    // chunk pair: global chunks 2acp, 2acp+1
  const int ar7 = arow & 7;
  const int aslot0 = (2 * acp) ^ ar7;
  const int aslot1 = (2 * acp + 1) ^ ar7;
  const float* asrc = Xf + (m0 + arow) * K_DIM + acp * 16;

  f32x4 rA0[4], rA1[4];  // single in-flight A set (halves 0/1)
  auto loadA0 = [&](int tt) {
    const float* s = asrc + tt * 64;
#pragma unroll
    for (int i = 0; i < 4; ++i) rA0[i] = *(const f32x4*)(s + i * 4);
  };
  auto loadA1 = [&](int tt) {
    const float* s = asrc + (long)128 * K_DIM + tt * 64;
#pragma unroll
    for (int i = 0; i < 4; ++i) rA1[i] = *(const f32x4*)(s + i * 4);
  };
  auto writeA0 = [&](int tt) {  // cvt+write from rA0 (half 0)
    bf16* dst = smem + (tt & 1) * 16384 + arow * 64;
    bf16x8 c0, c1;
#pragma unroll
    for (int j = 0; j < 4; ++j) {
      c0[j] = (bf16)rA0[0][j];
      c0[4 + j] = (bf16)rA0[1][j];
      c1[j] = (bf16)rA0[2][j];
      c1[4 + j] = (bf16)rA0[3][j];
    }
    *(bf16x8*)(dst + aslot0 * 8) = c0;
    *(bf16x8*)(dst + aslot1 * 8) = c1;
  };
  auto writeA1 = [&](int tt) {  // cvt+write from rA1 (half 1)
    bf16* dst = smem + (tt & 1) * 16384 + 8192 + arow * 64;
    bf16x8 c0, c1;
#pragma unroll
    for (int j = 0; j < 4; ++j) {
      c0[j] = (bf16)rA1[0][j];
      c0[4 + j] = (bf16)rA1[1][j];
      c1[j] = (bf16)rA1[2][j];
      c1[4 + j] = (bf16)rA1[3][j];
    }
    *(bf16x8*)(dst + aslot0 * 8) = c0;
    *(bf16x8*)(dst + aslot1 * 8) = c1;
  };

  // fragment read offsets: K-step q in [0,4) uses global chunk 2q+lh,
  // stored at slot (2q+lh)^(row&7); row&7 == lane&7 for 32-aligned bases.
  int sA[4];
#pragma unroll
  for (int q = 0; q < 4; ++q) sA[q] = ((2 * q + lh) ^ (lane & 7)) * 8;
  const int eAb = (wm * 128 + l31) * 64;  // + mi*2048 + sA[q]
  const int eBb = (wn * 64 + l31) * 64;   // + ni*2048 + sA[q]

  f32x16 acc[4][2] = {};  // 4 M-steps x 2 N-steps of 32x32

  // ---- prologue (R13) ----
  loadA0(0); loadA1(0);
  stageB(0, 0, 0); stageB(0, 1, 0);
  stageB(1, 0, 1); stageB(1, 1, 1);
  writeA0(0); writeA1(0);  // cvt waits loadA(0) only (oldest; stageB younger)
  loadA0(1); loadA1(1);    // rA now holds A(1)
  VMW(12);                 // retire B(0); keep B(1)+loadA(1) in flight
  LGKM(0);
  BAR();

  int bR = 0;  // B read buffer for tile t (t % 3)
  for (int t = 0; t < NT; ++t) {
    const bf16* Ab = smem + (t & 1) * 16384;
    const bf16* Bb = smem + 32768 + bR * 16384;
    const int bW = (bR >= 1) ? bR - 1 : 2;  // (t+2) % 3

    // group 1: all B frags + A mi0-1 (16 reads; bounded liveness)
    bf16x8 Bf[2][4], Af[2][4];
#pragma unroll
    for (int ni = 0; ni < 2; ++ni)
#pragma unroll
      for (int q = 0; q < 4; ++q)
        Bf[ni][q] = *(const bf16x8*)(Bb + eBb + ni * 2048 + sA[q]);
#pragma unroll
    for (int mi = 0; mi < 2; ++mi)
#pragma unroll
      for (int q = 0; q < 4; ++q)
        Af[mi][q] = *(const bf16x8*)(Ab + eAb + mi * 2048 + sA[q]);
    __builtin_amdgcn_s_setprio(1);
#pragma unroll
    for (int mi = 0; mi < 2; ++mi)
#pragma unroll
      for (int ni = 0; ni < 2; ++ni)
#pragma unroll
        for (int q = 0; q < 4; ++q)
          MFMA32(acc[mi][ni], Af[mi][q], Bf[ni][q]);
    __builtin_amdgcn_s_setprio(0);

    // group 2: A mi2-3 + all staging (no barrier between; 3-buf B)
    bf16x8 Cf[2][4];
#pragma unroll
    for (int mi = 0; mi < 2; ++mi)
#pragma unroll
      for (int q = 0; q < 4; ++q)
        Cf[mi][q] = *(const bf16x8*)(Ab + eAb + (2 + mi) * 2048 + sA[q]);
    if (t < NT - 2) { stageB(t + 2, 0, bW); stageB(t + 2, 1, bW); }
    // cvt forces vmcnt(4): retires stageB(t+1)+loadA(t+1), keeps stageB(t+2)
    if (t < NT - 1) { writeA0(t + 1); writeA1(t + 1); }
    if (t < NT - 2) { loadA0(t + 2); loadA1(t + 2); }  // WAR-safe: after cvt
    __builtin_amdgcn_s_setprio(1);
#pragma unroll
    for (int mi = 0; mi < 2; ++mi)
#pragma unroll
      for (int ni = 0; ni < 2; ++ni)
#pragma unroll
        for (int q = 0; q < 4; ++q)
          MFMA32(acc[2 + mi][ni], Cf[mi][q], Bf[ni][q]);
    __builtin_amdgcn_s_setprio(0);

    // A ds_writes visible to other waves at next tile (retired under MFMA).
    LGKM(0);
    // stageB(t+1) retired by the cvt's vmcnt; keep 12 newest in flight.
    if (t < NT - 2) {
      VMW(12);
    } else if (t == NT - 2) {
      VMW(0);
    }
    BAR();

    bR = (bR == 2) ? 0 : bR + 1;
  }

  // epilogue: C/D layout col = lane&31, row = (reg&3)+8*(reg>>2)+4*lh
  const long rbase = m0 + wm * 128 + 4 * lh;
  const int cbase = n0 + wn * 64 + l31;
  float bb[2] = {bias[cbase], bias[cbase + 32]};
#pragma unroll
  for (int mi = 0; mi < 4; ++mi)
#pragma unroll
    for (int ni = 0; ni < 2; ++ni) {
      const int col = cbase + ni * 32;
#pragma unroll
      for (int r = 0; r < 16; ++r) {
        const long row = rbase + mi * 32 + (r & 3) + 8 * (r >> 2);
        Y[row * N_DIM + col] = acc[mi][ni][r] + bb[ni];
      }
    }
}

extern "C" void kernel_launch(void* const* d_in, const int* in_sizes, int n_in,
                              void* d_out, int out_size, void* d_ws, size_t ws_size,
                              hipStream_t stream) {
  const float* x = (const float*)d_in[0];
  const float* W = (const float*)d_in[1];
  const float* b = (const float*)d_in[2];
  const float* lA = (const float*)d_in[3];
  const float* lB = (const float*)d_in[4];
  float* y = (float*)d_out;

  bf16* weff = (bf16*)d_ws;  // 2 MB

  weff_kernel<<<dim3(1024), dim3(256), 0, stream>>>(W, lA, lB, weff);

  const int grid = (M_DIM / 256) * (N_DIM / 256);  // 512
  gemm32m<<<dim3(grid), dim3(512), 0, stream>>>(x, weff, b, y);
}

// Round 16
// 98.191 us; speedup vs baseline: 1.0411x; 1.0411x over previous
//
#include <hip/hip_runtime.h>
#include <hip/hip_bf16.h>

// LoRALinear: y = x @ W^T + b + 1.0 * ((x @ A^T) @ B^T)
// W_eff = W + B@A (bf16, ws[0..2MB)).
// FINAL (R15 = R13 revert; R14's 32x32 shape regressed: 4-way LDS bank
// conflict in its fragment-read pattern + no MFMA-busy-time gain).
// Fused GEMM 256x256x64, ONE barrier per K-tile:
//   B TRIPLE-buffered (3x32KB, bufs t%3/(t+1)%3 read, (t+2)%3 write) ->
//   no B WAR hazard -> no mid-barrier.
//   A double-buffered (2x32KB), reg-staged fp32->bf16 fused cvt, 1-tile gap.
//   Tile: {read B0,B1,A0,A1; 32 MFMA; read C0,C1; stageB(t+2); writeA(t+1)
//   (cvt forces counted vmcnt: retires stageB(t+1) -> cross-wave B vis);
//   loadA(t+2); 32 MFMA; LGKM(0); VMW(12) counted; BAR}. LDS 160 KB.
// + XCD-bijective block swizzle, XOR bank swizzle both-sides, setprio.

typedef __bf16 bf16;
typedef bf16 bf16x8 __attribute__((ext_vector_type(8)));
typedef float f32x4 __attribute__((ext_vector_type(4)));

constexpr int K_DIM = 1024;
constexpr int N_DIM = 1024;
constexpr int M_DIM = 8 * 4096;
constexpr int NT = K_DIM / 64;  // 16 K-tiles
constexpr float SCALING = 16.0f / 16.0f;

// ---------------- W_eff = W + B@A, cast to bf16 ----------------
__global__ __launch_bounds__(256) void weff_kernel(
    const float* __restrict__ W, const float* __restrict__ A,
    const float* __restrict__ B, bf16* __restrict__ weff) {
  const int o = blockIdx.x;
  const int tid = threadIdx.x;
  float br[16];
#pragma unroll
  for (int r = 0; r < 16; ++r) br[r] = B[o * 16 + r];
#pragma unroll
  for (int j = 0; j < 4; ++j) {
    const int k = tid + j * 256;
    float s = W[o * K_DIM + k];
#pragma unroll
    for (int r = 0; r < 16; ++r) s += SCALING * br[r] * A[r * K_DIM + k];
    weff[o * K_DIM + k] = (bf16)s;
  }
}

// ---------------- fused 1-barrier 256x256 GEMM ----------------
__device__ __forceinline__ void async16(const void* g, void* l) {
  __builtin_amdgcn_global_load_lds(
      (const __attribute__((address_space(1))) void*)g,
      (__attribute__((address_space(3))) void*)l, 16, 0, 0);
}
#define BAR() __builtin_amdgcn_s_barrier()
#define LGKM(n) asm volatile("s_waitcnt lgkmcnt(" #n ")" ::: "memory")
#define VMW(n) asm volatile("s_waitcnt vmcnt(" #n ")" ::: "memory")
#define MFMA(d, a, b) d = __builtin_amdgcn_mfma_f32_16x16x32_bf16(a, b, d, 0, 0, 0)

// LDS (bf16 elems, 81920 = 160 KB):
//   A bufs: (t&1)*16384
//   B bufs: 32768 + (t%3)*16384
// Row = 64 bf16 = 8 chunks of 16 B; stored chunk s holds global chunk s^(row&7).

__global__ __launch_bounds__(512, 2) void gemm1c(
    const float* __restrict__ Xf, const bf16* __restrict__ Wf,
    const float* __restrict__ bias, float* __restrict__ Y) {
  __shared__ __align__(16) bf16 smem[81920];  // 160 KiB

  const int tid = threadIdx.x;
  const int lane = tid & 63;
  const int wid = tid >> 6;
  const int wm = wid >> 2;  // 0..1
  const int wn = wid & 3;   // 0..3
  const int l15 = lane & 15;
  const int lq = lane >> 4;

  // XCD-aware bijective swizzle (512 % 8 == 0)
  const int bid = blockIdx.x;
  const int wgid = (bid & 7) * 64 + (bid >> 3);
  const int bm = wgid >> 2;  // 0..127
  const int bn = wgid & 3;   // 0..3
  const long m0 = (long)bm * 256;
  const int n0 = bn * 256;

  // ---- B staging (global_load_lds, pre-swizzled source) ----
  const int srow = tid >> 3;               // 0..63
  const int gch = (tid & 7) ^ (srow & 7);  // inverse of read swizzle
  const bf16* wsrc = Wf + (long)(n0 + srow) * K_DIM + gch * 8;
  auto stageB = [&](int tt, int h, int buf) {
    bf16* dst = smem + 32768 + buf * 16384 + h * 8192 + tid * 8;
    const bf16* s = wsrc + (long)h * 128 * K_DIM + tt * 64;
    async16(s, dst);
    async16(s + 64 * K_DIM, dst + 4096);
  };

  // ---- A staging (reg-staged fp32 -> bf16, swizzled ds_write) ----
  const int arow = tid >> 2;  // 0..127
  const int acp = tid & 3;    // chunk pair: global chunks 2acp, 2acp+1
  const int ar7 = arow & 7;
  const int aslot0 = (2 * acp) ^ ar7;
  const int aslot1 = (2 * acp + 1) ^ ar7;
  const float* asrc = Xf + (m0 + arow) * K_DIM + acp * 16;

  f32x4 rA0[4], rA1[4];  // single in-flight A set (halves 0/1)
  auto loadA0 = [&](int tt) {
    const float* s = asrc + tt * 64;
#pragma unroll
    for (int i = 0; i < 4; ++i) rA0[i] = *(const f32x4*)(s + i * 4);
  };
  auto loadA1 = [&](int tt) {
    const float* s = asrc + (long)128 * K_DIM + tt * 64;
#pragma unroll
    for (int i = 0; i < 4; ++i) rA1[i] = *(const f32x4*)(s + i * 4);
  };
  auto writeA0 = [&](int tt) {  // cvt+write from rA0 (half 0)
    bf16* dst = smem + (tt & 1) * 16384 + arow * 64;
    bf16x8 c0, c1;
#pragma unroll
    for (int j = 0; j < 4; ++j) {
      c0[j] = (bf16)rA0[0][j];
      c0[4 + j] = (bf16)rA0[1][j];
      c1[j] = (bf16)rA0[2][j];
      c1[4 + j] = (bf16)rA0[3][j];
    }
    *(bf16x8*)(dst + aslot0 * 8) = c0;
    *(bf16x8*)(dst + aslot1 * 8) = c1;
  };
  auto writeA1 = [&](int tt) {  // cvt+write from rA1 (half 1)
    bf16* dst = smem + (tt & 1) * 16384 + 8192 + arow * 64;
    bf16x8 c0, c1;
#pragma unroll
    for (int j = 0; j < 4; ++j) {
      c0[j] = (bf16)rA1[0][j];
      c0[4 + j] = (bf16)rA1[1][j];
      c1[j] = (bf16)rA1[2][j];
      c1[4 + j] = (bf16)rA1[3][j];
    }
    *(bf16x8*)(dst + aslot0 * 8) = c0;
    *(bf16x8*)(dst + aslot1 * 8) = c1;
  };

  // fragment read offsets (XOR bank swizzle); kk=1 -> elem offset ^32
  const int key = l15 & 7;
  const int ck0 = lq ^ key;
  const int eA = (wm * 128 + l15) * 64 + ck0 * 8;
  const int eB = (wn * 64 + l15) * 64 + ck0 * 8;

  f32x4 acc[8][4] = {};

  // ---- prologue ----
  loadA0(0); loadA1(0);
  stageB(0, 0, 0); stageB(0, 1, 0);
  stageB(1, 0, 1); stageB(1, 1, 1);
  writeA0(0); writeA1(0);  // cvt waits loadA(0) only (oldest; stageB younger)
  loadA0(1); loadA1(1);    // rA now holds A(1)
  VMW(12);                 // retire B(0); keep B(1)+loadA(1) in flight
  LGKM(0);
  BAR();

  int bR = 0;  // B read buffer for tile t (t % 3)
  for (int t = 0; t < NT; ++t) {
    const bf16* Ab = smem + (t & 1) * 16384;
    const bf16* Bb = smem + 32768 + bR * 16384;
    const int bW = (bR >= 1) ? bR - 1 : 2;  // (t+2) % 3

    // group 1: B + A m0-3 (bounded frag liveness)
    bf16x8 B0[4], B1[4], A0[4], A1[4];
#pragma unroll
    for (int i = 0; i < 4; ++i) {
      B0[i] = *(const bf16x8*)(Bb + eB + i * 1024);
      B1[i] = *(const bf16x8*)(Bb + (eB ^ 32) + i * 1024);
      A0[i] = *(const bf16x8*)(Ab + eA + i * 1024);
      A1[i] = *(const bf16x8*)(Ab + (eA ^ 32) + i * 1024);
    }
    __builtin_amdgcn_s_setprio(1);
#pragma unroll
    for (int m = 0; m < 4; ++m)
#pragma unroll
      for (int n = 0; n < 4; ++n) MFMA(acc[m][n], A0[m], B0[n]);
#pragma unroll
    for (int m = 0; m < 4; ++m)
#pragma unroll
      for (int n = 0; n < 4; ++n) MFMA(acc[m][n], A1[m], B1[n]);
    __builtin_amdgcn_s_setprio(0);

    // group 2: A m4-7 + all staging (no barrier in between; 3-buf B)
    bf16x8 C0[4], C1[4];
#pragma unroll
    for (int i = 0; i < 4; ++i) {
      C0[i] = *(const bf16x8*)(Ab + eA + 4096 + i * 1024);
      C1[i] = *(const bf16x8*)(Ab + (eA ^ 32) + 4096 + i * 1024);
    }
    if (t < NT - 2) { stageB(t + 2, 0, bW); stageB(t + 2, 1, bW); }
    // cvt forces vmcnt(4): retires stageB(t+1)+loadA(t+1), keeps stageB(t+2)
    if (t < NT - 1) { writeA0(t + 1); writeA1(t + 1); }
    if (t < NT - 2) { loadA0(t + 2); loadA1(t + 2); }  // WAR-safe: after cvt
    __builtin_amdgcn_s_setprio(1);
#pragma unroll
    for (int m = 0; m < 4; ++m)
#pragma unroll
      for (int n = 0; n < 4; ++n) MFMA(acc[4 + m][n], C0[m], B0[n]);
#pragma unroll
    for (int m = 0; m < 4; ++m)
#pragma unroll
      for (int n = 0; n < 4; ++n) MFMA(acc[4 + m][n], C1[m], B1[n]);
    __builtin_amdgcn_s_setprio(0);

    // A ds_writes visible to other waves at next tile (retired under MFMA).
    LGKM(0);
    // stageB(t+1) already retired by the cvt's vmcnt(4); keep 12 newest
    // (stageB(t+2) 4 + loadA(t+2) 8) in flight. Tail: drain before last tiles.
    if (t < NT - 2) {
      VMW(12);
    } else if (t == NT - 2) {
      VMW(0);
    }
    BAR();

    bR = (bR == 2) ? 0 : bR + 1;
  }

  // epilogue: C/D layout col = lane&15, row = lq*4 + reg
  const long crow0 = m0 + wm * 128 + lq * 4;
  const int ccol0 = n0 + wn * 64 + l15;
  float bn4[4];
#pragma unroll
  for (int n = 0; n < 4; ++n) bn4[n] = bias[ccol0 + n * 16];
#pragma unroll
  for (int m = 0; m < 8; ++m)
#pragma unroll
    for (int n = 0; n < 4; ++n) {
      const int col = ccol0 + n * 16;
#pragma unroll
      for (int i = 0; i < 4; ++i)
        Y[(crow0 + m * 16 + i) * N_DIM + col] = acc[m][n][i] + bn4[n];
    }
}

extern "C" void kernel_launch(void* const* d_in, const int* in_sizes, int n_in,
                              void* d_out, int out_size, void* d_ws, size_t ws_size,
                              hipStream_t stream) {
  const float* x = (const float*)d_in[0];
  const float* W = (const float*)d_in[1];
  const float* b = (const float*)d_in[2];
  const float* lA = (const float*)d_in[3];
  const float* lB = (const float*)d_in[4];
  float* y = (float*)d_out;

  bf16* weff = (bf16*)d_ws;  // 2 MB

  weff_kernel<<<dim3(1024), dim3(256), 0, stream>>>(W, lA, lB, weff);

  const int grid = (M_DIM / 256) * (N_DIM / 256);  // 512
  gemm1c<<<dim3(grid), dim3(512), 0, stream>>>(x, weff, b, y);
}